// Round 20
// baseline (6097.453 us; speedup 1.0000x reference)
//
#include <hip/hip_runtime.h>
#include <stdint.h>

typedef unsigned int uint_t;

#define S_SEG 8192
#define CIN 128
#define COUT 256
#define LN_EPS 1e-5f
#define BM 64    // rows per block (16 per wave; 8 per 32-lane half)
#define XLD 132  // padded LDS leading dim for x rows (floats)

// order-preserving f32 <-> u32 keys for atomicMax-based float max
__device__ __forceinline__ uint_t fkey(float f) {
  uint_t b = __float_as_uint(f);
  return (b & 0x80000000u) ? ~b : (b | 0x80000000u);
}
__device__ __forceinline__ float funkey(uint_t k) {
  uint_t b = (k & 0x80000000u) ? (k ^ 0x80000000u) : ~k;
  return __uint_as_float(b);
}

// K0: init encoded-max buffer to key(-inf)   [passing, verbatim]
__global__ void k_xm_init(uint_t* __restrict__ enc) {
  enc[blockIdx.x * blockDim.x + threadIdx.x] = 0x007FFFFFu;
}

// K1: segment max via atomicMax on encoded floats   [passing, verbatim]
__global__ void k_xm_scatter(const float* __restrict__ x, const int* __restrict__ batch,
                             uint_t* __restrict__ enc, int N) {
  int r0 = blockIdx.x * 32;
  int c = threadIdx.x;  // 128 threads = channels
  int rend = r0 + 32; if (rend > N) rend = N;
  int cur = batch[r0];
  float m = -INFINITY;
  for (int r = r0; r < rend; ++r) {
    int b = batch[r];
    if (b != cur) {
      atomicMax(&enc[(size_t)cur * CIN + c], fkey(m));
      cur = b;
      m = -INFINITY;
    }
    m = fmaxf(m, x[(size_t)r * CIN + c]);
  }
  atomicMax(&enc[(size_t)cur * CIN + c], fkey(m));
}

// K2: decode in place; -inf (empty segment) -> 0   [passing, verbatim]
__global__ void k_xm_decode(uint_t* __restrict__ enc, float* __restrict__ xm) {
  int i = blockIdx.x * blockDim.x + threadIdx.x;
  float f = funkey(enc[i]);
  xm[i] = (f >= -3.0e38f && f <= 3.0e38f) ? f : 0.0f;
}

// K3 (vectorized, validated): xml[s][o] = gamma_b[o] - xm[s,:]·lambda_w[o,:]
__global__ void k_lambda_v2(const float* __restrict__ xm, const float* __restrict__ lw,
                            const float* __restrict__ gb, float* __restrict__ xml) {
  __shared__ float4 sx[256];  // 8 rows x 128 ch = 256 float4
  int s0 = blockIdx.x * 8;
  int o = threadIdx.x;  // 256 threads = out channels
  sx[o] = ((const float4*)(xm + (size_t)s0 * CIN))[o];
  __syncthreads();
  float acc[8];
#pragma unroll
  for (int j = 0; j < 8; ++j) acc[j] = 0.f;
  const float4* lr = (const float4*)(lw + (size_t)o * CIN);
#pragma unroll 8
  for (int c4 = 0; c4 < 32; ++c4) {
    float4 w = lr[c4];
#pragma unroll
    for (int j = 0; j < 8; ++j) {
      float4 v = sx[j * 32 + c4];
      acc[j] += w.x * v.x + w.y * v.y + w.z * v.z + w.w * v.w;
    }
  }
  float b = gb[o];
#pragma unroll
  for (int j = 0; j < 8; ++j) xml[(size_t)(s0 + j) * COUT + o] = b - acc[j];
}

// K3b: transpose gw -> gwT[k][cout] (128 KB), in the dead xm ws region.
__global__ void k_gwT(const float* __restrict__ gw, float* __restrict__ gwT) {
  int i = blockIdx.x * blockDim.x + threadIdx.x;  // 32768
  int k = i >> 8, c = i & 255;
  gwT[(size_t)k * COUT + c] = gw[(size_t)c * CIN + k];
}

// --- weight-buffer macros (suffixes start with a letter: R16 lesson) ---
#define WDECL(P) float4 P##a0, P##a1, P##a2, P##a3, P##b0, P##b1, P##b2, P##b3
#define WLOAD(P, kk) do {                                                     \
    const float* g_ = gwT + (size_t)((kk) * 4) * COUT + c0;                   \
    P##a0 = *(const float4*)(g_);           P##b0 = *(const float4*)(g_ + 4); \
    P##a1 = *(const float4*)(g_ + COUT);    P##b1 = *(const float4*)(g_ + COUT + 4); \
    P##a2 = *(const float4*)(g_ + 2*COUT);  P##b2 = *(const float4*)(g_ + 2*COUT + 4); \
    P##a3 = *(const float4*)(g_ + 3*COUT);  P##b3 = *(const float4*)(g_ + 3*COUT + 4); \
  } while (0)
#define WBURST(P, kk) do {                                                    \
    _Pragma("unroll")                                                         \
    for (int r = 0; r < 8; ++r) {                                             \
      float4 xv = *(const float4*)&xsrow[r * XLD + (kk) * 4];                 \
      accA[r].x = fmaf(xv.x, P##a0.x, accA[r].x);                             \
      accA[r].y = fmaf(xv.x, P##a0.y, accA[r].y);                             \
      accA[r].z = fmaf(xv.x, P##a0.z, accA[r].z);                             \
      accA[r].w = fmaf(xv.x, P##a0.w, accA[r].w);                             \
      accB[r].x = fmaf(xv.x, P##b0.x, accB[r].x);                             \
      accB[r].y = fmaf(xv.x, P##b0.y, accB[r].y);                             \
      accB[r].z = fmaf(xv.x, P##b0.z, accB[r].z);                             \
      accB[r].w = fmaf(xv.x, P##b0.w, accB[r].w);                             \
      accA[r].x = fmaf(xv.y, P##a1.x, accA[r].x);                             \
      accA[r].y = fmaf(xv.y, P##a1.y, accA[r].y);                             \
      accA[r].z = fmaf(xv.y, P##a1.z, accA[r].z);                             \
      accA[r].w = fmaf(xv.y, P##a1.w, accA[r].w);                             \
      accB[r].x = fmaf(xv.y, P##b1.x, accB[r].x);                             \
      accB[r].y = fmaf(xv.y, P##b1.y, accB[r].y);                             \
      accB[r].z = fmaf(xv.y, P##b1.z, accB[r].z);                             \
      accB[r].w = fmaf(xv.y, P##b1.w, accB[r].w);                             \
      accA[r].x = fmaf(xv.z, P##a2.x, accA[r].x);                             \
      accA[r].y = fmaf(xv.z, P##a2.y, accA[r].y);                             \
      accA[r].z = fmaf(xv.z, P##a2.z, accA[r].z);                             \
      accA[r].w = fmaf(xv.z, P##a2.w, accA[r].w);                             \
      accB[r].x = fmaf(xv.z, P##b2.x, accB[r].x);                             \
      accB[r].y = fmaf(xv.z, P##b2.y, accB[r].y);                             \
      accB[r].z = fmaf(xv.z, P##b2.z, accB[r].z);                             \
      accB[r].w = fmaf(xv.z, P##b2.w, accB[r].w);                             \
      accA[r].x = fmaf(xv.w, P##a3.x, accA[r].x);                             \
      accA[r].y = fmaf(xv.w, P##a3.y, accA[r].y);                             \
      accA[r].z = fmaf(xv.w, P##a3.z, accA[r].z);                             \
      accA[r].w = fmaf(xv.w, P##a3.w, accA[r].w);                             \
      accB[r].x = fmaf(xv.w, P##b3.x, accB[r].x);                             \
      accB[r].y = fmaf(xv.w, P##b3.y, accB[r].y);                             \
      accB[r].z = fmaf(xv.w, P##b3.z, accB[r].z);                             \
      accB[r].w = fmaf(xv.w, P##b3.w, accB[r].w);                             \
    }                                                                         \
  } while (0)

// K4 v9: = v8 with prefetch depth 4 (buffers A,B,C,D; kc step 4, ROLLED).
// Live regs ~4x32 + 64 acc + ~20 = ~215 < 256 cap (launch_bounds(256,2)).
// Single variable vs R19: deeper weight pipeline to cover L2 latency.
__global__ __launch_bounds__(256, 2) void k_main_v9(
    const float* __restrict__ x, const int* __restrict__ batch,
    const float* __restrict__ gwT, const float* __restrict__ xml,
    const float* __restrict__ lnw, const float* __restrict__ lnb,
    const float* __restrict__ prelu, float* __restrict__ out, int N) {
  __shared__ float xs[BM * XLD];  // 33,792 B : x rows, all 128 k

  const int tid = threadIdx.x;
  const int ty = tid >> 6;          // wave id
  const int l = tid & 63;
  const int rh = l >> 5;            // half-wave row-octet select
  const int c0 = (l & 31) * 8;      // 8 cols per lane
  const size_t row0 = (size_t)blockIdx.x * BM;
  const int rbase = ty * 16 + rh * 8;

  // stage x rows: 64 rows x 32 float4 chunks = 2048, 8 per thread
#pragma unroll
  for (int i = 0; i < 8; ++i) {
    int idx = tid + i * 256;
    int r = idx >> 5, ch = idx & 31;
    size_t gr = row0 + r;
    if (gr >= (size_t)N) gr = (size_t)N - 1;  // N%64==0: never fires
    *(float4*)&xs[r * XLD + ch * 4] = *(const float4*)(x + gr * CIN + ch * 4);
  }
  __syncthreads();

  const float* xsrow = &xs[rbase * XLD];
  float4 accA[8], accB[8];
#pragma unroll
  for (int r = 0; r < 8; ++r) {
    accA[r] = (float4){0.f, 0.f, 0.f, 0.f};
    accB[r] = (float4){0.f, 0.f, 0.f, 0.f};
  }

  WDECL(A); WDECL(B); WDECL(C); WDECL(D);
  WLOAD(A, 0); WLOAD(B, 1); WLOAD(C, 2);
  for (int kc = 0; kc < 32; kc += 4) {   // ROLLED (R18 lesson)
    WLOAD(D, kc + 3);
    WBURST(A, kc);
    if (kc + 4 < 32) WLOAD(A, kc + 4);
    WBURST(B, kc + 1);
    if (kc + 5 < 32) WLOAD(B, kc + 5);
    WBURST(C, kc + 2);
    if (kc + 6 < 32) WLOAD(C, kc + 6);
    WBURST(D, kc + 3);
  }

  // epilogue: lane's row = rbase + r; LN reduce across the 32-lane half
  const float4 lwa = *(const float4*)(lnw + c0);
  const float4 lwb = *(const float4*)(lnw + c0 + 4);
  const float4 lba = *(const float4*)(lnb + c0);
  const float4 lbb = *(const float4*)(lnb + c0 + 4);
  const float asl = prelu[0];
#pragma unroll
  for (int r = 0; r < 8; ++r) {
    size_t row = row0 + (size_t)(rbase + r);
    if (row >= (size_t)N) continue;      // uniform within the half
    const float* xmlr = xml + (size_t)batch[row] * COUT;
    float4 ma = *(const float4*)(xmlr + c0);
    float4 mb = *(const float4*)(xmlr + c0 + 4);
    float4 va, vb;
    va.x = accA[r].x + ma.x; va.y = accA[r].y + ma.y;
    va.z = accA[r].z + ma.z; va.w = accA[r].w + ma.w;
    vb.x = accB[r].x + mb.x; vb.y = accB[r].y + mb.y;
    vb.z = accB[r].z + mb.z; vb.w = accB[r].w + mb.w;
    float sum = va.x + va.y + va.z + va.w + vb.x + vb.y + vb.z + vb.w;
    float ssq = va.x * va.x + va.y * va.y + va.z * va.z + va.w * va.w +
                vb.x * vb.x + vb.y * vb.y + vb.z * vb.z + vb.w * vb.w;
#pragma unroll
    for (int m = 1; m < 32; m <<= 1) {   // reduce within the 32-lane half
      sum += __shfl_xor(sum, m);
      ssq += __shfl_xor(ssq, m);
    }
    float mu = sum * (1.f / 256.f);
    float var = ssq * (1.f / 256.f) - mu * mu;
    float rs = rsqrtf(var + LN_EPS);
    float4 oa, ob; float t;
    t = (va.x - mu) * rs * lwa.x + lba.x; oa.x = (t >= 0.f) ? t : asl * t;
    t = (va.y - mu) * rs * lwa.y + lba.y; oa.y = (t >= 0.f) ? t : asl * t;
    t = (va.z - mu) * rs * lwa.z + lba.z; oa.z = (t >= 0.f) ? t : asl * t;
    t = (va.w - mu) * rs * lwa.w + lba.w; oa.w = (t >= 0.f) ? t : asl * t;
    t = (vb.x - mu) * rs * lwb.x + lbb.x; ob.x = (t >= 0.f) ? t : asl * t;
    t = (vb.y - mu) * rs * lwb.y + lbb.y; ob.y = (t >= 0.f) ? t : asl * t;
    t = (vb.z - mu) * rs * lwb.z + lbb.z; ob.z = (t >= 0.f) ? t : asl * t;
    t = (vb.w - mu) * rs * lwb.w + lbb.w; ob.w = (t >= 0.f) ? t : asl * t;
    float* orow = out + row * COUT + c0;
    *(float4*)(orow) = oa;
    *(float4*)(orow + 4) = ob;
  }
}

extern "C" void kernel_launch(void* const* d_in, const int* in_sizes, int n_in,
                              void* d_out, int out_size, void* d_ws, size_t ws_size,
                              hipStream_t stream) {
  const float* x     = (const float*)d_in[0];
  const int*   batch = (const int*)d_in[1];
  const float* gw    = (const float*)d_in[2];
  const float* gb    = (const float*)d_in[3];
  const float* lw    = (const float*)d_in[4];
  const float* lnw   = (const float*)d_in[5];
  const float* lnb   = (const float*)d_in[6];
  const float* pa    = (const float*)d_in[7];
  float* out = (float*)d_out;
  const int N = in_sizes[0] / CIN;

  // ws, TOTAL 12 MB (verified): [0,4MB) enc/xm, gwT reuses it after k_lambda;
  // [4MB,12MB) xml.
  char* w8 = (char*)d_ws;
  uint_t* enc = (uint_t*)w8;
  float* xm   = (float*)w8;                  // alias of enc (in-place decode)
  float* gwT  = (float*)w8;                  // alias of xm, valid AFTER k_lambda
  float* xml  = (float*)(w8 + 4194304);

  k_xm_init<<<(S_SEG * CIN) / 256, 256, 0, stream>>>(enc);
  k_xm_scatter<<<(N + 31) / 32, CIN, 0, stream>>>(x, batch, enc, N);
  k_xm_decode<<<(S_SEG * CIN) / 256, 256, 0, stream>>>(enc, xm);
  k_lambda_v2<<<S_SEG / 8, COUT, 0, stream>>>(xm, lw, gb, xml);
  k_gwT<<<(COUT * CIN) / 256, 256, 0, stream>>>(gw, gwT);  // xm dead now
  k_main_v9<<<(N + BM - 1) / BM, 256, 0, stream>>>(x, batch, gwT, xml, lnw, lnb, pa, out, N);
}

// Round 21
// 1090.475 us; speedup vs baseline: 5.5916x; 5.5916x over previous
//
#include <hip/hip_runtime.h>
#include <stdint.h>

typedef unsigned int uint_t;

#define S_SEG 8192
#define CIN 128
#define COUT 256
#define LN_EPS 1e-5f
#define BM 64    // rows per block (16 per wave; 8 per 32-lane half)
#define XLD 132  // padded LDS leading dim for x rows (floats)

// order-preserving f32 <-> u32 keys for atomicMax-based float max
__device__ __forceinline__ uint_t fkey(float f) {
  uint_t b = __float_as_uint(f);
  return (b & 0x80000000u) ? ~b : (b | 0x80000000u);
}
__device__ __forceinline__ float funkey(uint_t k) {
  uint_t b = (k & 0x80000000u) ? (k ^ 0x80000000u) : ~k;
  return __uint_as_float(b);
}

// K0: init encoded-max buffer to key(-inf)   [passing, verbatim]
__global__ void k_xm_init(uint_t* __restrict__ enc) {
  enc[blockIdx.x * blockDim.x + threadIdx.x] = 0x007FFFFFu;
}

// K1: segment max via atomicMax on encoded floats   [passing, verbatim]
__global__ void k_xm_scatter(const float* __restrict__ x, const int* __restrict__ batch,
                             uint_t* __restrict__ enc, int N) {
  int r0 = blockIdx.x * 32;
  int c = threadIdx.x;  // 128 threads = channels
  int rend = r0 + 32; if (rend > N) rend = N;
  int cur = batch[r0];
  float m = -INFINITY;
  for (int r = r0; r < rend; ++r) {
    int b = batch[r];
    if (b != cur) {
      atomicMax(&enc[(size_t)cur * CIN + c], fkey(m));
      cur = b;
      m = -INFINITY;
    }
    m = fmaxf(m, x[(size_t)r * CIN + c]);
  }
  atomicMax(&enc[(size_t)cur * CIN + c], fkey(m));
}

// K2: decode in place; -inf (empty segment) -> 0   [passing, verbatim]
__global__ void k_xm_decode(uint_t* __restrict__ enc, float* __restrict__ xm) {
  int i = blockIdx.x * blockDim.x + threadIdx.x;
  float f = funkey(enc[i]);
  xm[i] = (f >= -3.0e38f && f <= 3.0e38f) ? f : 0.0f;
}

// K3 (vectorized, validated): xml[s][o] = gamma_b[o] - xm[s,:]·lambda_w[o,:]
__global__ void k_lambda_v2(const float* __restrict__ xm, const float* __restrict__ lw,
                            const float* __restrict__ gb, float* __restrict__ xml) {
  __shared__ float4 sx[256];  // 8 rows x 128 ch = 256 float4
  int s0 = blockIdx.x * 8;
  int o = threadIdx.x;  // 256 threads = out channels
  sx[o] = ((const float4*)(xm + (size_t)s0 * CIN))[o];
  __syncthreads();
  float acc[8];
#pragma unroll
  for (int j = 0; j < 8; ++j) acc[j] = 0.f;
  const float4* lr = (const float4*)(lw + (size_t)o * CIN);
#pragma unroll 8
  for (int c4 = 0; c4 < 32; ++c4) {
    float4 w = lr[c4];
#pragma unroll
    for (int j = 0; j < 8; ++j) {
      float4 v = sx[j * 32 + c4];
      acc[j] += w.x * v.x + w.y * v.y + w.z * v.z + w.w * v.w;
    }
  }
  float b = gb[o];
#pragma unroll
  for (int j = 0; j < 8; ++j) xml[(size_t)(s0 + j) * COUT + o] = b - acc[j];
}

// K3b: transpose gw -> gwT[k][cout] (128 KB), in the dead xm ws region.
__global__ void k_gwT(const float* __restrict__ gw, float* __restrict__ gwT) {
  int i = blockIdx.x * blockDim.x + threadIdx.x;  // 32768
  int k = i >> 8, c = i & 255;
  gwT[(size_t)k * COUT + c] = gw[(size_t)c * CIN + k];
}

// --- v8 weight-buffer macros (suffixes start with a letter: R16 lesson) ---
#define WDECL(P) float4 P##a0, P##a1, P##a2, P##a3, P##b0, P##b1, P##b2, P##b3
#define WLOAD(P, kk) do {                                                     \
    const float* g_ = gwT + (size_t)((kk) * 4) * COUT + c0;                   \
    P##a0 = *(const float4*)(g_);           P##b0 = *(const float4*)(g_ + 4); \
    P##a1 = *(const float4*)(g_ + COUT);    P##b1 = *(const float4*)(g_ + COUT + 4); \
    P##a2 = *(const float4*)(g_ + 2*COUT);  P##b2 = *(const float4*)(g_ + 2*COUT + 4); \
    P##a3 = *(const float4*)(g_ + 3*COUT);  P##b3 = *(const float4*)(g_ + 3*COUT + 4); \
  } while (0)
#define WBURST(P, kk) do {                                                    \
    _Pragma("unroll")                                                         \
    for (int r = 0; r < 8; ++r) {                                             \
      float4 xv = *(const float4*)&xsrow[r * XLD + (kk) * 4];                 \
      accA[r].x = fmaf(xv.x, P##a0.x, accA[r].x);                             \
      accA[r].y = fmaf(xv.x, P##a0.y, accA[r].y);                             \
      accA[r].z = fmaf(xv.x, P##a0.z, accA[r].z);                             \
      accA[r].w = fmaf(xv.x, P##a0.w, accA[r].w);                             \
      accB[r].x = fmaf(xv.x, P##b0.x, accB[r].x);                             \
      accB[r].y = fmaf(xv.x, P##b0.y, accB[r].y);                             \
      accB[r].z = fmaf(xv.x, P##b0.z, accB[r].z);                             \
      accB[r].w = fmaf(xv.x, P##b0.w, accB[r].w);                             \
      accA[r].x = fmaf(xv.y, P##a1.x, accA[r].x);                             \
      accA[r].y = fmaf(xv.y, P##a1.y, accA[r].y);                             \
      accA[r].z = fmaf(xv.y, P##a1.z, accA[r].z);                             \
      accA[r].w = fmaf(xv.y, P##a1.w, accA[r].w);                             \
      accB[r].x = fmaf(xv.y, P##b1.x, accB[r].x);                             \
      accB[r].y = fmaf(xv.y, P##b1.y, accB[r].y);                             \
      accB[r].z = fmaf(xv.y, P##b1.z, accB[r].z);                             \
      accB[r].w = fmaf(xv.y, P##b1.w, accB[r].w);                             \
      accA[r].x = fmaf(xv.z, P##a2.x, accA[r].x);                             \
      accA[r].y = fmaf(xv.z, P##a2.y, accA[r].y);                             \
      accA[r].z = fmaf(xv.z, P##a2.z, accA[r].z);                             \
      accA[r].w = fmaf(xv.z, P##a2.w, accA[r].w);                             \
      accB[r].x = fmaf(xv.z, P##b2.x, accB[r].x);                             \
      accB[r].y = fmaf(xv.z, P##b2.y, accB[r].y);                             \
      accB[r].z = fmaf(xv.z, P##b2.z, accB[r].z);                             \
      accB[r].w = fmaf(xv.z, P##b2.w, accB[r].w);                             \
      accA[r].x = fmaf(xv.w, P##a3.x, accA[r].x);                             \
      accA[r].y = fmaf(xv.w, P##a3.y, accA[r].y);                             \
      accA[r].z = fmaf(xv.w, P##a3.z, accA[r].z);                             \
      accA[r].w = fmaf(xv.w, P##a3.w, accA[r].w);                             \
      accB[r].x = fmaf(xv.w, P##b3.x, accB[r].x);                             \
      accB[r].y = fmaf(xv.w, P##b3.y, accB[r].y);                             \
      accB[r].z = fmaf(xv.w, P##b3.z, accB[r].z);                             \
      accB[r].w = fmaf(xv.w, P##b3.w, accB[r].w);                             \
    }                                                                         \
  } while (0)

// K4 v8 (R19-verbatim, best verified: k_main ~940us, VGPR 72, no spill).
// launch_bounds(256,2) = VGPR cap 256 (spill-proof); ROLLED kc loop with
// depth-2 prefetch. R18 (unroll+cap128) and R20 (depth-4) both proved any
// higher register plan melts down into scratch spill -- this is the optimum.
__global__ __launch_bounds__(256, 2) void k_main_v8(
    const float* __restrict__ x, const int* __restrict__ batch,
    const float* __restrict__ gwT, const float* __restrict__ xml,
    const float* __restrict__ lnw, const float* __restrict__ lnb,
    const float* __restrict__ prelu, float* __restrict__ out, int N) {
  __shared__ float xs[BM * XLD];  // 33,792 B : x rows, all 128 k

  const int tid = threadIdx.x;
  const int ty = tid >> 6;          // wave id
  const int l = tid & 63;
  const int rh = l >> 5;            // half-wave row-octet select
  const int c0 = (l & 31) * 8;      // 8 cols per lane
  const size_t row0 = (size_t)blockIdx.x * BM;
  const int rbase = ty * 16 + rh * 8;

  // stage x rows: 64 rows x 32 float4 chunks = 2048, 8 per thread
#pragma unroll
  for (int i = 0; i < 8; ++i) {
    int idx = tid + i * 256;
    int r = idx >> 5, ch = idx & 31;
    size_t gr = row0 + r;
    if (gr >= (size_t)N) gr = (size_t)N - 1;  // N%64==0: never fires
    *(float4*)&xs[r * XLD + ch * 4] = *(const float4*)(x + gr * CIN + ch * 4);
  }
  __syncthreads();

  const float* xsrow = &xs[rbase * XLD];
  float4 accA[8], accB[8];
#pragma unroll
  for (int r = 0; r < 8; ++r) {
    accA[r] = (float4){0.f, 0.f, 0.f, 0.f};
    accB[r] = (float4){0.f, 0.f, 0.f, 0.f};
  }

  WDECL(A); WDECL(B);
  WLOAD(A, 0);
  for (int kc = 0; kc < 32; kc += 2) {   // ROLLED, depth-2 (verified optimum)
    WLOAD(B, kc + 1);                    // kc+1 <= 31 always
    WBURST(A, kc);
    int kn = (kc + 2 < 32) ? (kc + 2) : 31;
    WLOAD(A, kn);                        // last iter: harmless re-load
    WBURST(B, kc + 1);
  }

  // epilogue: lane's row = rbase + r; LN reduce across the 32-lane half
  const float4 lwa = *(const float4*)(lnw + c0);
  const float4 lwb = *(const float4*)(lnw + c0 + 4);
  const float4 lba = *(const float4*)(lnb + c0);
  const float4 lbb = *(const float4*)(lnb + c0 + 4);
  const float asl = prelu[0];
#pragma unroll
  for (int r = 0; r < 8; ++r) {
    size_t row = row0 + (size_t)(rbase + r);
    if (row >= (size_t)N) continue;      // uniform within the half
    const float* xmlr = xml + (size_t)batch[row] * COUT;
    float4 ma = *(const float4*)(xmlr + c0);
    float4 mb = *(const float4*)(xmlr + c0 + 4);
    float4 va, vb;
    va.x = accA[r].x + ma.x; va.y = accA[r].y + ma.y;
    va.z = accA[r].z + ma.z; va.w = accA[r].w + ma.w;
    vb.x = accB[r].x + mb.x; vb.y = accB[r].y + mb.y;
    vb.z = accB[r].z + mb.z; vb.w = accB[r].w + mb.w;
    float sum = va.x + va.y + va.z + va.w + vb.x + vb.y + vb.z + vb.w;
    float ssq = va.x * va.x + va.y * va.y + va.z * va.z + va.w * va.w +
                vb.x * vb.x + vb.y * vb.y + vb.z * vb.z + vb.w * vb.w;
#pragma unroll
    for (int m = 1; m < 32; m <<= 1) {   // reduce within the 32-lane half
      sum += __shfl_xor(sum, m);
      ssq += __shfl_xor(ssq, m);
    }
    float mu = sum * (1.f / 256.f);
    float var = ssq * (1.f / 256.f) - mu * mu;
    float rs = rsqrtf(var + LN_EPS);
    float4 oa, ob; float t;
    t = (va.x - mu) * rs * lwa.x + lba.x; oa.x = (t >= 0.f) ? t : asl * t;
    t = (va.y - mu) * rs * lwa.y + lba.y; oa.y = (t >= 0.f) ? t : asl * t;
    t = (va.z - mu) * rs * lwa.z + lba.z; oa.z = (t >= 0.f) ? t : asl * t;
    t = (va.w - mu) * rs * lwa.w + lba.w; oa.w = (t >= 0.f) ? t : asl * t;
    t = (vb.x - mu) * rs * lwb.x + lbb.x; ob.x = (t >= 0.f) ? t : asl * t;
    t = (vb.y - mu) * rs * lwb.y + lbb.y; ob.y = (t >= 0.f) ? t : asl * t;
    t = (vb.z - mu) * rs * lwb.z + lbb.z; ob.z = (t >= 0.f) ? t : asl * t;
    t = (vb.w - mu) * rs * lwb.w + lbb.w; ob.w = (t >= 0.f) ? t : asl * t;
    float* orow = out + row * COUT + c0;
    *(float4*)(orow) = oa;
    *(float4*)(orow + 4) = ob;
  }
}

extern "C" void kernel_launch(void* const* d_in, const int* in_sizes, int n_in,
                              void* d_out, int out_size, void* d_ws, size_t ws_size,
                              hipStream_t stream) {
  const float* x     = (const float*)d_in[0];
  const int*   batch = (const int*)d_in[1];
  const float* gw    = (const float*)d_in[2];
  const float* gb    = (const float*)d_in[3];
  const float* lw    = (const float*)d_in[4];
  const float* lnw   = (const float*)d_in[5];
  const float* lnb   = (const float*)d_in[6];
  const float* pa    = (const float*)d_in[7];
  float* out = (float*)d_out;
  const int N = in_sizes[0] / CIN;

  // ws, TOTAL 12 MB (verified): [0,4MB) enc/xm, gwT reuses it after k_lambda;
  // [4MB,12MB) xml.
  char* w8 = (char*)d_ws;
  uint_t* enc = (uint_t*)w8;
  float* xm   = (float*)w8;                  // alias of enc (in-place decode)
  float* gwT  = (float*)w8;                  // alias of xm, valid AFTER k_lambda
  float* xml  = (float*)(w8 + 4194304);

  k_xm_init<<<(S_SEG * CIN) / 256, 256, 0, stream>>>(enc);
  k_xm_scatter<<<(N + 31) / 32, CIN, 0, stream>>>(x, batch, enc, N);
  k_xm_decode<<<(S_SEG * CIN) / 256, 256, 0, stream>>>(enc, xm);
  k_lambda_v2<<<S_SEG / 8, COUT, 0, stream>>>(xm, lw, gb, xml);
  k_gwT<<<(COUT * CIN) / 256, 256, 0, stream>>>(gw, gwT);  // xm dead now
  k_main_v8<<<(N + BM - 1) / BM, 256, 0, stream>>>(x, batch, gwT, xml, lnw, lnb, pa, out, N);
}